// Round 6
// baseline (408.434 us; speedup 1.0000x reference)
//
#include <hip/hip_runtime.h>
#include <stdint.h>

// ---------------------------------------------------------------------------
// RoIHead: out = crop_and_resize(feature, rois) @ (W_fc @ [W_loc|W_score])
//                + (b_fc @ [W_loc|W_score] + [b_loc|b_score])
// 413 GF -> 32 GF. Floor: 411 MB W_fc + 100 MB pool = ~81 us HBM.
// R6: (1) A-prefetch distance 0.5 -> 2 phases (rE->even putA, rO->odd putA);
// (2) native (__bf16) casts replace 4-VALU f2bf everywhere;
// (3) ATTRIBUTION PROBE: fused pool+gemm1 launched twice (2nd into dummy ws)
//     so next round's delta measures the fused kernel exactly.
// ---------------------------------------------------------------------------

typedef float          f32x4 __attribute__((ext_vector_type(4)));
typedef __bf16         bfx8  __attribute__((ext_vector_type(8)));
typedef __bf16         bfx4  __attribute__((ext_vector_type(4)));
typedef __bf16         bfx2  __attribute__((ext_vector_type(2)));

#define KBIG 25088   // 7*7*512
#define NMID 4096    // FC_OUT
#define NROIS 2000
#define G1BLOCKS 784 // 392 m-tiles x 2 k-splits
#define SPLITS 28    // gemm2 K-splits (392 BK steps = 28*14)

__device__ __forceinline__ void gll16(const void* g, void* l) {
  __builtin_amdgcn_global_load_lds(
      (const __attribute__((address_space(1))) void*)(uintptr_t)(g),
      (__attribute__((address_space(3))) void*)(uintptr_t)(l), 16, 0, 0);
}

// ---------------------------------------------------------------------------
// prep: blocks 0..2047 build WcatT[128][4096] bf16 (zero-padded cols>=105);
//       blocks 2048..2175 compute bc[c] = b_fc . Wcat[:,c] + bias[c].
// ---------------------------------------------------------------------------
__global__ __launch_bounds__(256) void k_prep(const float* __restrict__ Wl,
                                              const float* __restrict__ Ws,
                                              const float* __restrict__ bfc,
                                              const float* __restrict__ bl,
                                              const float* __restrict__ bs,
                                              unsigned short* __restrict__ WcatT,
                                              float* __restrict__ bc) {
  if (blockIdx.x < 2048) {
    int idx = blockIdx.x * 256 + threadIdx.x;
    int c = idx >> 12, k = idx & 4095;
    float v = 0.0f;
    if (c < 84)       v = Wl[k * 84 + c];
    else if (c < 105) v = Ws[k * 21 + (c - 84)];
    ((__bf16*)WcatT)[idx] = (__bf16)v;
  } else {
    int c = blockIdx.x - 2048;   // 0..127
    int t = threadIdx.x;
    __shared__ float red[256];
    float p = 0.0f;
    if (c < 105) {
      for (int k = t; k < 4096; k += 256) {
        float w = (c < 84) ? Wl[k * 84 + c] : Ws[k * 21 + (c - 84)];
        p += bfc[k] * w;
      }
    }
    red[t] = p;
    __syncthreads();
    for (int s = 128; s > 0; s >>= 1) {
      if (t < s) red[t] += red[t + s];
      __syncthreads();
    }
    if (t == 0) {
      float bias = (c < 84) ? bl[c] : (c < 105 ? bs[c - 84] : 0.0f);
      bc[c] = (c < 105) ? (red[0] + bias) : 0.0f;
    }
  }
}

// ---------------------------------------------------------------------------
// Fused: blocks [0,784) = GEMM1 (mt = bx>>1, ksplit = bx&1), [784,2784) = pool.
// GEMM1: Pg1[sp][n][m] f32 partial of (W_fc @ WcatT^T)^T.
//   A: coalesced global->reg, cvt (native), swizzled ds_write; prefetch
//      distance = 2 FULL phases (rE feeds even putA, rO feeds odd putA).
//   B: gll16, pre-inverse-swizzled source.
//   Phase: putA(c) [auto vmcnt(8)], stageB(c+1), loadA(c+2), vmcnt(12)+
//   lgkmcnt(0), s_barrier, compute(c), s_barrier. No drain in the loop.
// ---------------------------------------------------------------------------
__global__ __launch_bounds__(256, 3) void k_pool_gemm1(
    const float* __restrict__ F, const float* __restrict__ rois,
    const int* __restrict__ ihp, const int* __restrict__ iwp,
    unsigned short* __restrict__ A,
    const float* __restrict__ Wfc, const unsigned short* __restrict__ WcatT,
    float* __restrict__ Pg1) {
  const int t = threadIdx.x;
  __shared__ __align__(16) char sA[16384];   // [2][64 rows][128 B]
  __shared__ __align__(16) char sB[32768];   // [2][128 rows][128 B]
  if (blockIdx.x < G1BLOCKS) {
    // ---------------- GEMM1 ----------------
    const int lane = t & 63, wid = t >> 6;
    const int l15 = lane & 15, l4 = lane >> 4;
    const int mt = blockIdx.x >> 1, sp = blockIdx.x & 1;
    const int m0 = mt * 64;
    const int kbase = sp * 2048;
    const int jlog = (t & 7) ^ ((t >> 3) & 7);
    f32x4 acc[8] = {};
    f32x4 rE[4], rO[4];

    const float* abase = Wfc + (size_t)m0 * NMID + kbase;
    const int arw = t >> 4;          // row within 16-row group
    const int acl = (t & 15) * 4;    // float col
    const int ac16 = (t & 15) >> 1;  // 16B chunk within row
    const int ahalf = t & 1;         // 8B half of the chunk

    auto loadA = [&](f32x4* d, int c) {
#pragma unroll
      for (int i = 0; i < 4; ++i)
        d[i] = *(const f32x4*)(abase + (size_t)(i * 16 + arw) * NMID + c * 64 + acl);
    };
    auto putA = [&](const f32x4* r, int off) {
#pragma unroll
      for (int i = 0; i < 4; ++i) {
        const int row = i * 16 + arw;
        bfx4 p;
#pragma unroll
        for (int j = 0; j < 4; ++j) p[j] = (__bf16)r[i][j];
        *(bfx4*)(sA + off + row * 128 + ((ac16 ^ (row & 7)) << 4) + ahalf * 8) = p;
      }
    };
    auto stageB = [&](int c, int off) {
#pragma unroll
      for (int q = 0; q < 4; ++q)
        gll16(WcatT + (size_t)(q * 32 + (t >> 3)) * NMID + kbase + c * 64 + jlog * 8,
              sB + off + q * 4096 + wid * 1024);
    };
    auto compute = [&](int aoff, int boff) {
#pragma unroll
      for (int kk = 0; kk < 2; ++kk) {
        const int ar = wid * 16 + l15;
        bfx8 af = *(const bfx8*)(sA + aoff + ar * 128 + ((((kk << 2) + l4) ^ (ar & 7)) << 4));
        bfx8 bfr[8];
#pragma unroll
        for (int nt = 0; nt < 8; ++nt) {
          const int row = nt * 16 + l15;
          bfr[nt] = *(const bfx8*)(sB + boff + row * 128 + ((((kk << 2) + l4) ^ (row & 7)) << 4));
        }
#pragma unroll
        for (int nt = 0; nt < 8; ++nt)
          acc[nt] = __builtin_amdgcn_mfma_f32_16x16x32_bf16(af, bfr[nt], acc[nt], 0, 0, 0);
      }
    };

    // prologue issue order: A(0) < B(0) < A(1)
    loadA(rE, 0);
    __builtin_amdgcn_sched_barrier(0);
    stageB(0, 0);
    __builtin_amdgcn_sched_barrier(0);
    loadA(rO, 1);
    __builtin_amdgcn_sched_barrier(0);

    for (int cc = 0; cc < 16; ++cc) {
      const int c0 = cc * 2;
      // even: compute c0 (sA buf0, sB buf0)
      putA(rE, 0);                             // A(c0), loaded 2 phases ago
      stageB(c0 + 1, 16384);
      __builtin_amdgcn_sched_barrier(0);
      loadA(rE, (c0 + 2 < 32) ? c0 + 2 : 31);  // for next even putA
      __builtin_amdgcn_sched_barrier(0);
      asm volatile("s_waitcnt vmcnt(12) lgkmcnt(0)" ::: "memory");
      __builtin_amdgcn_s_barrier();
      __builtin_amdgcn_sched_barrier(0);
      compute(0, 0);
      __builtin_amdgcn_s_barrier();
      // odd: compute c0+1 (sA buf1, sB buf1)
      putA(rO, 8192);                          // A(c0+1), loaded 2 phases ago
      stageB((c0 + 2 < 32) ? c0 + 2 : 31, 0);
      __builtin_amdgcn_sched_barrier(0);
      loadA(rO, (c0 + 3 < 32) ? c0 + 3 : 31);  // for next odd putA
      __builtin_amdgcn_sched_barrier(0);
      asm volatile("s_waitcnt vmcnt(12) lgkmcnt(0)" ::: "memory");
      __builtin_amdgcn_s_barrier();
      __builtin_amdgcn_sched_barrier(0);
      compute(8192, 16384);
      __builtin_amdgcn_s_barrier();
    }
    asm volatile("s_waitcnt vmcnt(0)" ::: "memory");
    // epilogue: D col(lane&15)=n, row((lane>>4)*4+i)=m -> 16B f32 stores
#pragma unroll
    for (int nt = 0; nt < 8; ++nt) {
      const int n = nt * 16 + l15;
      float* dst = Pg1 + ((size_t)sp * 128 + n) * KBIG + m0 + wid * 16 + l4 * 4;
      *(f32x4*)dst = acc[nt];
    }
  } else {
    // ---------------- pool (next-cell prefetch) ----------------
    const int r = blockIdx.x - G1BLOCKS;
    const float ih = (float)ihp[0], iw = (float)iwp[0];
    const float y1 = rois[r * 4 + 0] / ih;
    const float x1 = rois[r * 4 + 1] / iw;
    const float y2 = rois[r * 4 + 2] / ih;
    const float x2 = rois[r * 4 + 3] / iw;
    const float sy = (y2 - y1) * 49.0f / 6.0f;
    const float sx = (x2 - x1) * 49.0f / 6.0f;
    const int ch = t * 2;
    __bf16* __restrict__ Arow = (__bf16*)(A + (size_t)r * KBIG);

    auto cellcoords = [&](int cell, int& o00, int& o01, int& o10, int& o11,
                          float& yl, float& xl, bool& valid) {
      const int iy = cell / 7, ix = cell - iy * 7;
      const float in_y = y1 * 49.0f + (float)iy * sy;
      const float in_x = x1 * 49.0f + (float)ix * sx;
      const float y0f = floorf(in_y), x0f = floorf(in_x);
      yl = in_y - y0f; xl = in_x - x0f;
      const int y0  = (int)fminf(fmaxf(y0f, 0.0f), 49.0f);
      const int y1i = (int)fminf(fmaxf(y0f + 1.0f, 0.0f), 49.0f);
      const int x0  = (int)fminf(fmaxf(x0f, 0.0f), 49.0f);
      const int x1i = (int)fminf(fmaxf(x0f + 1.0f, 0.0f), 49.0f);
      valid = (in_y >= 0.0f) && (in_y <= 49.0f) && (in_x >= 0.0f) && (in_x <= 49.0f);
      o00 = (y0 * 50 + x0) * 512;  o01 = (y0 * 50 + x1i) * 512;
      o10 = (y1i * 50 + x0) * 512; o11 = (y1i * 50 + x1i) * 512;
    };

    int o00, o01, o10, o11; float yl, xl; bool valid;
    cellcoords(0, o00, o01, o10, o11, yl, xl, valid);
    float2 f00 = *(const float2*)&F[o00 + ch];
    float2 f01 = *(const float2*)&F[o01 + ch];
    float2 f10 = *(const float2*)&F[o10 + ch];
    float2 f11 = *(const float2*)&F[o11 + ch];

    for (int cell = 0; cell < 49; ++cell) {
      const float2 g00 = f00, g01 = f01, g10 = f10, g11 = f11;
      const float pyl = yl, pxl = xl;
      const bool pv = valid;
      if (cell < 48) {
        cellcoords(cell + 1, o00, o01, o10, o11, yl, xl, valid);
        f00 = *(const float2*)&F[o00 + ch];
        f01 = *(const float2*)&F[o01 + ch];
        f10 = *(const float2*)&F[o10 + ch];
        f11 = *(const float2*)&F[o11 + ch];
      }
      float oA = 0.0f, oB = 0.0f;
      if (pv) {
        float t0 = g00.x * (1.0f - pxl) + g01.x * pxl;
        float t1 = g00.y * (1.0f - pxl) + g01.y * pxl;
        float b0 = g10.x * (1.0f - pxl) + g11.x * pxl;
        float b1 = g10.y * (1.0f - pxl) + g11.y * pxl;
        oA = t0 * (1.0f - pyl) + b0 * pyl;
        oB = t1 * (1.0f - pyl) + b1 * pyl;
      }
      bfx2 v; v[0] = (__bf16)oA; v[1] = (__bf16)oB;
      *(bfx2*)(Arow + cell * 512 + ch) = v;
    }
  }
}

// ---------------------------------------------------------------------------
// addcvt: WcT[n][m] bf16 = Pg1[0][n][m] + Pg1[1][n][m]
// ---------------------------------------------------------------------------
__global__ __launch_bounds__(256) void k_addcvt(const float* __restrict__ Pg1,
                                                unsigned short* __restrict__ WcT) {
  const size_t i = ((size_t)blockIdx.x * 256 + threadIdx.x) * 8;  // < 128*25088
  f32x4 a0 = *(const f32x4*)(Pg1 + i);
  f32x4 a1 = *(const f32x4*)(Pg1 + i + 4);
  f32x4 b0 = *(const f32x4*)(Pg1 + 3211264 + i);
  f32x4 b1 = *(const f32x4*)(Pg1 + 3211264 + i + 4);
  bfx8 o;
#pragma unroll
  for (int j = 0; j < 4; ++j) {
    o[j]     = (__bf16)(a0[j] + b0[j]);
    o[j + 4] = (__bf16)(a1[j] + b1[j]);
  }
  *(bfx8*)(WcT + i) = o;
}

// ---------------------------------------------------------------------------
// GEMM2: P[mt*28+sp][64][128] f32 = pool_tile(mt) @ WcT_slice(sp).
// Counted-vmcnt double buffer: stage(c+1); vmcnt(6); barrier; compute(c);
// barrier. One 6-op staging group per region -> count is order-robust.
// ---------------------------------------------------------------------------
__global__ __launch_bounds__(256) void k_gemm2(const unsigned short* __restrict__ Ap,
                                               const unsigned short* __restrict__ WcT,
                                               float* __restrict__ P) {
  __shared__ __align__(16) char S[49152];
  const int t = threadIdx.x;
  const int lane = t & 63, wid = t >> 6;
  const int wm = wid >> 1, wn = wid & 1;
  const int l15 = lane & 15, l4 = lane >> 4;
  const int mt = blockIdx.x, sp = blockIdx.y;
  const int kbase = sp * 896;     // 14 BK-steps of 64
  const int jlog = (t & 7) ^ ((t >> 3) & 7);
  f32x4 acc[2][4] = {};

  int ar0 = mt * 64 + (t >> 3);
  int ar1 = ar0 + 32;
  if (ar0 > NROIS - 1) ar0 = NROIS - 1;
  if (ar1 > NROIS - 1) ar1 = NROIS - 1;
  const unsigned short* asrc0 = Ap + (size_t)ar0 * KBIG + jlog * 8;
  const unsigned short* asrc1 = Ap + (size_t)ar1 * KBIG + jlog * 8;

  auto stage2 = [&](int c, int off) {
    const int k0 = kbase + c * 64;
    gll16(asrc0 + k0, S + off + wid * 1024);
    gll16(asrc1 + k0, S + off + 4096 + wid * 1024);
#pragma unroll
    for (int q = 0; q < 4; ++q)
      gll16(WcT + (size_t)(q * 32 + (t >> 3)) * KBIG + k0 + jlog * 8,
            S + off + 8192 + q * 4096 + wid * 1024);
  };
  auto compute2 = [&](int off) {
#pragma unroll
    for (int kh = 0; kh < 2; ++kh) {
      bfx8 af[2], bfr[4];
#pragma unroll
      for (int mi = 0; mi < 2; ++mi) {
        const int row = wm * 32 + mi * 16 + l15;
        af[mi] = *(const bfx8*)(S + off + row * 128 + ((((kh << 2) + l4) ^ (row & 7)) << 4));
      }
#pragma unroll
      for (int ni = 0; ni < 4; ++ni) {
        const int row = wn * 64 + ni * 16 + l15;
        bfr[ni] = *(const bfx8*)(S + off + 8192 + row * 128 + ((((kh << 2) + l4) ^ (row & 7)) << 4));
      }
#pragma unroll
      for (int mi = 0; mi < 2; ++mi)
#pragma unroll
        for (int ni = 0; ni < 4; ++ni)
          acc[mi][ni] = __builtin_amdgcn_mfma_f32_16x16x32_bf16(af[mi], bfr[ni], acc[mi][ni], 0, 0, 0);
    }
  };

  stage2(0, 0);
  for (int cc = 0; cc < 7; ++cc) {
    const int c0 = cc * 2;
    stage2(c0 + 1, 24576);
    asm volatile("s_waitcnt vmcnt(6)" ::: "memory");
    __builtin_amdgcn_s_barrier();
    __builtin_amdgcn_sched_barrier(0);
    compute2(0);
    __builtin_amdgcn_s_barrier();
    stage2((c0 + 2 < 14) ? c0 + 2 : 13, 0);
    asm volatile("s_waitcnt vmcnt(6)" ::: "memory");
    __builtin_amdgcn_s_barrier();
    __builtin_amdgcn_sched_barrier(0);
    compute2(24576);
    __builtin_amdgcn_s_barrier();
  }
  asm volatile("s_waitcnt vmcnt(0)" ::: "memory");
  float* out = P + (size_t)(mt * SPLITS + sp) * 8192;
#pragma unroll
  for (int mi = 0; mi < 2; ++mi)
#pragma unroll
    for (int ni = 0; ni < 4; ++ni)
#pragma unroll
      for (int i = 0; i < 4; ++i)
        out[(wm * 32 + mi * 16 + l4 * 4 + i) * 128 + wn * 64 + ni * 16 + l15] = acc[mi][ni][i];
}

// ---------------------------------------------------------------------------
// reduce: sum 28 K-split partials + bias, scatter into the two outputs.
// ---------------------------------------------------------------------------
__global__ __launch_bounds__(128) void k_reduce(const float* __restrict__ P,
                                                const float* __restrict__ bc,
                                                float* __restrict__ out) {
  const int m = blockIdx.x;     // 0..1999
  const int c = threadIdx.x;    // 0..127
  if (c >= 105) return;
  const int mt = m >> 6, r = m & 63;
  float sum = 0.0f;
#pragma unroll
  for (int s = 0; s < SPLITS; ++s)
    sum += P[(size_t)(mt * SPLITS + s) * 8192 + r * 128 + c];
  sum += bc[c];
  if (c < 84) out[m * 84 + c] = sum;
  else        out[168000 + m * 21 + (c - 84)] = sum;
}

// ---------------------------------------------------------------------------
extern "C" void kernel_launch(void* const* d_in, const int* in_sizes, int n_in,
                              void* d_out, int out_size, void* d_ws, size_t ws_size,
                              hipStream_t stream) {
  const float* F    = (const float*)d_in[0];
  const float* rois = (const float*)d_in[1];
  const int*   ih   = (const int*)d_in[2];
  const int*   iw   = (const int*)d_in[3];
  const float* Wfc  = (const float*)d_in[4];
  const float* bfc  = (const float*)d_in[5];
  const float* Wl   = (const float*)d_in[6];
  const float* bl   = (const float*)d_in[7];
  const float* Ws   = (const float*)d_in[8];
  const float* bs   = (const float*)d_in[9];
  (void)in_sizes; (void)n_in; (void)out_size; (void)ws_size;

  char* ws = (char*)d_ws;
  // ws layout (bytes):
  //   pool  bf16 [2000][25088]      @ 0          (100,352,000)
  //   WcatT bf16 [128][4096]        @ 100352000  (1,048,576)
  //   WcT   bf16 [128][25088]       @ 101400576  (6,422,528)
  //   bc    f32  [128]              @ 107823104  (512)
  //   P     f32  [896][64][128]     @ 107823616  (29,360,128)
  //   Pg1   f32  [2][128][25088]    @ 137183744  (25,690,112)
  //   --- attribution-probe dummies ---
  //   pool2 bf16                    @ 162873856  (100,352,000)
  //   Pg12  f32                     @ 263225856  (25,690,112)   total ~289 MB
  unsigned short* Apool = (unsigned short*)(ws);
  unsigned short* WcatT = (unsigned short*)(ws + 100352000);
  unsigned short* WcT   = (unsigned short*)(ws + 101400576);
  float*          bc    = (float*)(ws + 107823104);
  float*          P     = (float*)(ws + 107823616);
  float*          Pg1   = (float*)(ws + 137183744);
  unsigned short* Apool2= (unsigned short*)(ws + 162873856);
  float*          Pg12  = (float*)(ws + 263225856);
  float*          out   = (float*)d_out;

  k_prep      <<<2176, 256, 0, stream>>>(Wl, Ws, bfc, bl, bs, WcatT, bc);
  k_pool_gemm1<<<G1BLOCKS + NROIS, 256, 0, stream>>>(F, rois, ih, iw, Apool,
                                                     Wfc, WcatT, Pg1);
  // attribution probe: identical second pass into dummy buffers
  k_pool_gemm1<<<G1BLOCKS + NROIS, 256, 0, stream>>>(F, rois, ih, iw, Apool2,
                                                     Wfc, WcatT, Pg12);
  k_addcvt    <<<1568, 256, 0, stream>>>(Pg1, WcT);
  k_gemm2     <<<dim3(32, SPLITS), 256, 0, stream>>>(Apool, WcT, P);
  k_reduce    <<<NROIS, 128, 0, stream>>>(P, bc, out);
}

// Round 7
// 252.261 us; speedup vs baseline: 1.6191x; 1.6191x over previous
//
#include <hip/hip_runtime.h>
#include <stdint.h>

// ---------------------------------------------------------------------------
// RoIHead: out = crop_and_resize(feature, rois) @ (W_fc @ [W_loc|W_score])
//                + (b_fc @ [W_loc|W_score] + [b_loc|b_score])
// 413 GF -> 32 GF. Floor: 411 MB W_fc + 100 MB pool = ~81 us HBM.
// R7: page-locality rewrite of gemm1. R1-R6 all read A as rows x 256B at
// 16KB stride (one page touch per ~1600cyc -> DRAM activate-bound, 2.8 TB/s).
// Now BM=16, k unsplit: per thread an 8-chunk (2KB/row) register batch is
// issued back-to-back every 8 phases -> 8 sequential touches per page.
// B: global->reg->LDS so ALL vmem waits are compiler reg-dep waits (exact,
// FIFO-aware); loop has no manual vmcnt. gemm1 writes WcT bf16 directly
// (k-split gone -> addcvt/Pg1 deleted).
// ---------------------------------------------------------------------------

typedef float          f32x4 __attribute__((ext_vector_type(4)));
typedef __bf16         bfx8  __attribute__((ext_vector_type(8)));
typedef __bf16         bfx4  __attribute__((ext_vector_type(4)));
typedef __bf16         bfx2  __attribute__((ext_vector_type(2)));

#define KBIG 25088   // 7*7*512
#define NMID 4096    // FC_OUT
#define NROIS 2000
#define G1BLOCKS 1568 // 25088/16
#define SPLITS 28    // gemm2 K-splits (392 BK steps = 28*14)

__device__ __forceinline__ void gll16(const void* g, void* l) {
  __builtin_amdgcn_global_load_lds(
      (const __attribute__((address_space(1))) void*)(uintptr_t)(g),
      (__attribute__((address_space(3))) void*)(uintptr_t)(l), 16, 0, 0);
}

// ---------------------------------------------------------------------------
// prep: blocks 0..2047 build WcatT[128][4096] bf16 (zero-padded cols>=105);
//       blocks 2048..2175 compute bc[c] = b_fc . Wcat[:,c] + bias[c].
// ---------------------------------------------------------------------------
__global__ __launch_bounds__(256) void k_prep(const float* __restrict__ Wl,
                                              const float* __restrict__ Ws,
                                              const float* __restrict__ bfc,
                                              const float* __restrict__ bl,
                                              const float* __restrict__ bs,
                                              unsigned short* __restrict__ WcatT,
                                              float* __restrict__ bc) {
  if (blockIdx.x < 2048) {
    int idx = blockIdx.x * 256 + threadIdx.x;
    int c = idx >> 12, k = idx & 4095;
    float v = 0.0f;
    if (c < 84)       v = Wl[k * 84 + c];
    else if (c < 105) v = Ws[k * 21 + (c - 84)];
    ((__bf16*)WcatT)[idx] = (__bf16)v;
  } else {
    int c = blockIdx.x - 2048;   // 0..127
    int t = threadIdx.x;
    __shared__ float red[256];
    float p = 0.0f;
    if (c < 105) {
      for (int k = t; k < 4096; k += 256) {
        float w = (c < 84) ? Wl[k * 84 + c] : Ws[k * 21 + (c - 84)];
        p += bfc[k] * w;
      }
    }
    red[t] = p;
    __syncthreads();
    for (int s = 128; s > 0; s >>= 1) {
      if (t < s) red[t] += red[t + s];
      __syncthreads();
    }
    if (t == 0) {
      float bias = (c < 84) ? bl[c] : (c < 105 ? bs[c - 84] : 0.0f);
      bc[c] = (c < 105) ? (red[0] + bias) : 0.0f;
    }
  }
}

// ---------------------------------------------------------------------------
// Fused: blocks [0,1568) = GEMM1 (BM=16, full K), [1568,3568) = pool.
// GEMM1 per block: WcT[0:128][m0:m0+16] = (Wfc[m0:m0+16][:] @ WcatT^T)^T.
//   64 phases of BK=64. A: 8-chunk reg batch (thread t: row t>>4, its 16B
//   slice of chunks c..c+8, addresses +256B apart -> page-sequential).
//   B: global->reg (4x dwordx4) -> swizzled ds_write. LDS dbuf 36KB.
//   Phase: putA(c+1) putB(c+1) | loadB(c+2) [batch A at u==6] | lgkm(0) |
//   bar | compute(c) | bar.  No manual vmcnt anywhere.
// ---------------------------------------------------------------------------
__global__ __launch_bounds__(256, 4) void k_pool_gemm1(
    const float* __restrict__ F, const float* __restrict__ rois,
    const int* __restrict__ ihp, const int* __restrict__ iwp,
    unsigned short* __restrict__ A,
    const float* __restrict__ Wfc, const unsigned short* __restrict__ WcatT,
    unsigned short* __restrict__ WcT) {
  const int t = threadIdx.x;
  __shared__ __align__(16) char sA[4096];    // [2][16 rows][128 B]
  __shared__ __align__(16) char sB[32768];   // [2][128 rows][128 B]
  if (blockIdx.x < G1BLOCKS) {
    // ---------------- GEMM1 ----------------
    const int lane = t & 63, wid = t >> 6;
    const int l15 = lane & 15, l4 = lane >> 4;
    const int m0 = blockIdx.x * 16;
    f32x4 acc[2] = {};
    f32x4 rA[8];        // 8-chunk A batch: 2KB-per-row page-sequential window
    f32x4 rB[4];        // one B phase (64B/thread), raw bf16 bits

    const float* abase = Wfc + (size_t)(m0 + (t >> 4)) * NMID;  // own row
    const int acol = t & 15;          // 16B slice within a 256B chunk
    const int arow = t >> 4;
    const unsigned short* bbase = WcatT + (size_t)(t >> 1) * NMID + (t & 1) * 32;
    const int brow = t >> 1;

    auto loadAbatch = [&](int cBase) {
#pragma unroll
      for (int j = 0; j < 8; ++j)
        rA[j] = *(const f32x4*)(abase + (cBase + j) * 64 + acol * 4);
    };
    auto loadB = [&](int c) {
#pragma unroll
      for (int i = 0; i < 4; ++i)
        rB[i] = *(const f32x4*)(bbase + c * 64 + i * 8);
    };
    // putA: chunk data in rA[idx] (idx compile-time), write 8B swizzled
    auto putA = [&](int idx, int buf) {
      f32x4 v = rA[idx];
      bfx4 p;
#pragma unroll
      for (int j = 0; j < 4; ++j) p[j] = (__bf16)v[j];
      *(bfx4*)(sA + buf * 2048 + arow * 128 +
               (((acol >> 1) ^ (arow & 7)) << 4) + (acol & 1) * 8) = p;
    };
    auto putB = [&](int buf) {
#pragma unroll
      for (int i = 0; i < 4; ++i) {
        const int j = (t & 1) * 4 + i;
        *(f32x4*)(sB + buf * 16384 + brow * 128 + ((j ^ (brow & 7)) << 4)) = rB[i];
      }
    };
    auto compute = [&](int buf) {
#pragma unroll
      for (int kk = 0; kk < 2; ++kk) {
        bfx8 af = *(const bfx8*)(sA + buf * 2048 + l15 * 128 +
                                 ((((kk << 2) + l4) ^ (l15 & 7)) << 4));
#pragma unroll
        for (int nt = 0; nt < 2; ++nt) {
          const int row = wid * 32 + nt * 16 + l15;
          bfx8 bf = *(const bfx8*)(sB + buf * 16384 + row * 128 +
                                   ((((kk << 2) + l4) ^ (row & 7)) << 4));
          acc[nt] = __builtin_amdgcn_mfma_f32_16x16x32_bf16(af, bf, acc[nt], 0, 0, 0);
        }
      }
    };

    // prologue: chunks 0..7 batch + B(0); stage chunk 0 into buf0; load B(1)
    loadAbatch(0);
    __builtin_amdgcn_sched_barrier(0);
    loadB(0);
    __builtin_amdgcn_sched_barrier(0);
    putA(0, 0);
    putB(0);
    __builtin_amdgcn_sched_barrier(0);
    loadB(1);
    __builtin_amdgcn_sched_barrier(0);
    asm volatile("s_waitcnt lgkmcnt(0)" ::: "memory");

    // main: groups cc=0..6 fully regular (batch for next group at u==6)
    for (int cc = 0; cc < 7; ++cc) {
#pragma unroll
      for (int u = 0; u < 8; ++u) {
        const int c = cc * 8 + u;
        putA((u + 1) & 7, (u + 1) & 1);   // chunk c+1
        putB((u + 1) & 1);                // B(c+1) from rB
        __builtin_amdgcn_sched_barrier(0);
        loadB(c + 2);
        if (u == 6) loadAbatch(c + 2);    // chunks of group cc+1
        __builtin_amdgcn_sched_barrier(0);
        asm volatile("s_waitcnt lgkmcnt(0)" ::: "memory");
        __builtin_amdgcn_s_barrier();
        compute(u & 1);
        __builtin_amdgcn_s_barrier();
      }
    }
    // epilogue group: chunks 56..63 already in rA
#pragma unroll
    for (int u = 0; u < 8; ++u) {
      const int c = 56 + u;
      if (u < 7) {
        putA((u + 1) & 7, (u + 1) & 1);
        putB((u + 1) & 1);
        __builtin_amdgcn_sched_barrier(0);
        if (u < 6) loadB(c + 2);
        __builtin_amdgcn_sched_barrier(0);
        asm volatile("s_waitcnt lgkmcnt(0)" ::: "memory");
      }
      __builtin_amdgcn_s_barrier();
      compute(u & 1);
      __builtin_amdgcn_s_barrier();
    }
    // store: D col(l15)=n-frag col, row(l4*4+i)=m -> 4 consecutive m = 8B bf16
#pragma unroll
    for (int nt = 0; nt < 2; ++nt) {
      const int n = wid * 32 + nt * 16 + l15;
      bfx4 pk;
#pragma unroll
      for (int i = 0; i < 4; ++i) pk[i] = (__bf16)acc[nt][i];
      *(bfx4*)(WcT + (size_t)n * KBIG + m0 + l4 * 4) = pk;
    }
  } else {
    // ---------------- pool (next-cell prefetch) ----------------
    const int r = blockIdx.x - G1BLOCKS;
    const float ih = (float)ihp[0], iw = (float)iwp[0];
    const float y1 = rois[r * 4 + 0] / ih;
    const float x1 = rois[r * 4 + 1] / iw;
    const float y2 = rois[r * 4 + 2] / ih;
    const float x2 = rois[r * 4 + 3] / iw;
    const float sy = (y2 - y1) * 49.0f / 6.0f;
    const float sx = (x2 - x1) * 49.0f / 6.0f;
    const int ch = t * 2;
    __bf16* __restrict__ Arow = (__bf16*)(A + (size_t)r * KBIG);

    auto cellcoords = [&](int cell, int& o00, int& o01, int& o10, int& o11,
                          float& yl, float& xl, bool& valid) {
      const int iy = cell / 7, ix = cell - iy * 7;
      const float in_y = y1 * 49.0f + (float)iy * sy;
      const float in_x = x1 * 49.0f + (float)ix * sx;
      const float y0f = floorf(in_y), x0f = floorf(in_x);
      yl = in_y - y0f; xl = in_x - x0f;
      const int y0  = (int)fminf(fmaxf(y0f, 0.0f), 49.0f);
      const int y1i = (int)fminf(fmaxf(y0f + 1.0f, 0.0f), 49.0f);
      const int x0  = (int)fminf(fmaxf(x0f, 0.0f), 49.0f);
      const int x1i = (int)fminf(fmaxf(x0f + 1.0f, 0.0f), 49.0f);
      valid = (in_y >= 0.0f) && (in_y <= 49.0f) && (in_x >= 0.0f) && (in_x <= 49.0f);
      o00 = (y0 * 50 + x0) * 512;  o01 = (y0 * 50 + x1i) * 512;
      o10 = (y1i * 50 + x0) * 512; o11 = (y1i * 50 + x1i) * 512;
    };

    int o00, o01, o10, o11; float yl, xl; bool valid;
    cellcoords(0, o00, o01, o10, o11, yl, xl, valid);
    float2 f00 = *(const float2*)&F[o00 + ch];
    float2 f01 = *(const float2*)&F[o01 + ch];
    float2 f10 = *(const float2*)&F[o10 + ch];
    float2 f11 = *(const float2*)&F[o11 + ch];

    for (int cell = 0; cell < 49; ++cell) {
      const float2 g00 = f00, g01 = f01, g10 = f10, g11 = f11;
      const float pyl = yl, pxl = xl;
      const bool pv = valid;
      if (cell < 48) {
        cellcoords(cell + 1, o00, o01, o10, o11, yl, xl, valid);
        f00 = *(const float2*)&F[o00 + ch];
        f01 = *(const float2*)&F[o01 + ch];
        f10 = *(const float2*)&F[o10 + ch];
        f11 = *(const float2*)&F[o11 + ch];
      }
      float oA = 0.0f, oB = 0.0f;
      if (pv) {
        float t0 = g00.x * (1.0f - pxl) + g01.x * pxl;
        float t1 = g00.y * (1.0f - pxl) + g01.y * pxl;
        float b0 = g10.x * (1.0f - pxl) + g11.x * pxl;
        float b1 = g10.y * (1.0f - pxl) + g11.y * pxl;
        oA = t0 * (1.0f - pyl) + b0 * pyl;
        oB = t1 * (1.0f - pyl) + b1 * pyl;
      }
      bfx2 v; v[0] = (__bf16)oA; v[1] = (__bf16)oB;
      *(bfx2*)(Arow + cell * 512 + ch) = v;
    }
  }
}

// ---------------------------------------------------------------------------
// GEMM2: P[mt*28+sp][64][128] f32 = pool_tile(mt) @ WcT_slice(sp).
// Counted-vmcnt double buffer: stage(c+1); vmcnt(6); barrier; compute(c);
// barrier. One 6-op staging group per region -> count is order-robust.
// ---------------------------------------------------------------------------
__global__ __launch_bounds__(256) void k_gemm2(const unsigned short* __restrict__ Ap,
                                               const unsigned short* __restrict__ WcT,
                                               float* __restrict__ P) {
  __shared__ __align__(16) char S[49152];
  const int t = threadIdx.x;
  const int lane = t & 63, wid = t >> 6;
  const int wm = wid >> 1, wn = wid & 1;
  const int l15 = lane & 15, l4 = lane >> 4;
  const int mt = blockIdx.x, sp = blockIdx.y;
  const int kbase = sp * 896;     // 14 BK-steps of 64
  const int jlog = (t & 7) ^ ((t >> 3) & 7);
  f32x4 acc[2][4] = {};

  int ar0 = mt * 64 + (t >> 3);
  int ar1 = ar0 + 32;
  if (ar0 > NROIS - 1) ar0 = NROIS - 1;
  if (ar1 > NROIS - 1) ar1 = NROIS - 1;
  const unsigned short* asrc0 = Ap + (size_t)ar0 * KBIG + jlog * 8;
  const unsigned short* asrc1 = Ap + (size_t)ar1 * KBIG + jlog * 8;

  auto stage2 = [&](int c, int off) {
    const int k0 = kbase + c * 64;
    gll16(asrc0 + k0, S + off + wid * 1024);
    gll16(asrc1 + k0, S + off + 4096 + wid * 1024);
#pragma unroll
    for (int q = 0; q < 4; ++q)
      gll16(WcT + (size_t)(q * 32 + (t >> 3)) * KBIG + k0 + jlog * 8,
            S + off + 8192 + q * 4096 + wid * 1024);
  };
  auto compute2 = [&](int off) {
#pragma unroll
    for (int kh = 0; kh < 2; ++kh) {
      bfx8 af[2], bfr[4];
#pragma unroll
      for (int mi = 0; mi < 2; ++mi) {
        const int row = wm * 32 + mi * 16 + l15;
        af[mi] = *(const bfx8*)(S + off + row * 128 + ((((kh << 2) + l4) ^ (row & 7)) << 4));
      }
#pragma unroll
      for (int ni = 0; ni < 4; ++ni) {
        const int row = wn * 64 + ni * 16 + l15;
        bfr[ni] = *(const bfx8*)(S + off + 8192 + row * 128 + ((((kh << 2) + l4) ^ (row & 7)) << 4));
      }
#pragma unroll
      for (int mi = 0; mi < 2; ++mi)
#pragma unroll
        for (int ni = 0; ni < 4; ++ni)
          acc[mi][ni] = __builtin_amdgcn_mfma_f32_16x16x32_bf16(af[mi], bfr[ni], acc[mi][ni], 0, 0, 0);
    }
  };

  stage2(0, 0);
  for (int cc = 0; cc < 7; ++cc) {
    const int c0 = cc * 2;
    stage2(c0 + 1, 24576);
    asm volatile("s_waitcnt vmcnt(6)" ::: "memory");
    __builtin_amdgcn_s_barrier();
    __builtin_amdgcn_sched_barrier(0);
    compute2(0);
    __builtin_amdgcn_s_barrier();
    stage2((c0 + 2 < 14) ? c0 + 2 : 13, 0);
    asm volatile("s_waitcnt vmcnt(6)" ::: "memory");
    __builtin_amdgcn_s_barrier();
    __builtin_amdgcn_sched_barrier(0);
    compute2(24576);
    __builtin_amdgcn_s_barrier();
  }
  asm volatile("s_waitcnt vmcnt(0)" ::: "memory");
  float* out = P + (size_t)(mt * SPLITS + sp) * 8192;
#pragma unroll
  for (int mi = 0; mi < 2; ++mi)
#pragma unroll
    for (int ni = 0; ni < 4; ++ni)
#pragma unroll
      for (int i = 0; i < 4; ++i)
        out[(wm * 32 + mi * 16 + l4 * 4 + i) * 128 + wn * 64 + ni * 16 + l15] = acc[mi][ni][i];
}

// ---------------------------------------------------------------------------
// reduce: sum 28 K-split partials + bias, scatter into the two outputs.
// ---------------------------------------------------------------------------
__global__ __launch_bounds__(128) void k_reduce(const float* __restrict__ P,
                                                const float* __restrict__ bc,
                                                float* __restrict__ out) {
  const int m = blockIdx.x;     // 0..1999
  const int c = threadIdx.x;    // 0..127
  if (c >= 105) return;
  const int mt = m >> 6, r = m & 63;
  float sum = 0.0f;
#pragma unroll
  for (int s = 0; s < SPLITS; ++s)
    sum += P[(size_t)(mt * SPLITS + s) * 8192 + r * 128 + c];
  sum += bc[c];
  if (c < 84) out[m * 84 + c] = sum;
  else        out[168000 + m * 21 + (c - 84)] = sum;
}

// ---------------------------------------------------------------------------
extern "C" void kernel_launch(void* const* d_in, const int* in_sizes, int n_in,
                              void* d_out, int out_size, void* d_ws, size_t ws_size,
                              hipStream_t stream) {
  const float* F    = (const float*)d_in[0];
  const float* rois = (const float*)d_in[1];
  const int*   ih   = (const int*)d_in[2];
  const int*   iw   = (const int*)d_in[3];
  const float* Wfc  = (const float*)d_in[4];
  const float* bfc  = (const float*)d_in[5];
  const float* Wl   = (const float*)d_in[6];
  const float* bl   = (const float*)d_in[7];
  const float* Ws   = (const float*)d_in[8];
  const float* bs   = (const float*)d_in[9];
  (void)in_sizes; (void)n_in; (void)out_size; (void)ws_size;

  char* ws = (char*)d_ws;
  // ws layout (bytes):
  //   pool  bf16 [2000][25088]      @ 0          (100,352,000)
  //   WcatT bf16 [128][4096]        @ 100352000  (1,048,576)
  //   WcT   bf16 [128][25088]       @ 101400576  (6,422,528)
  //   bc    f32  [128]              @ 107823104  (512)
  //   P     f32  [896][64][128]     @ 107823616  (29,360,128)  total ~137 MB
  unsigned short* Apool = (unsigned short*)(ws);
  unsigned short* WcatT = (unsigned short*)(ws + 100352000);
  unsigned short* WcT   = (unsigned short*)(ws + 101400576);
  float*          bc    = (float*)(ws + 107823104);
  float*          P     = (float*)(ws + 107823616);
  float*          out   = (float*)d_out;

  k_prep      <<<2176, 256, 0, stream>>>(Wl, Ws, bfc, bl, bs, WcatT, bc);
  k_pool_gemm1<<<G1BLOCKS + NROIS, 256, 0, stream>>>(F, rois, ih, iw, Apool,
                                                     Wfc, WcatT, WcT);
  k_gemm2     <<<dim3(32, SPLITS), 256, 0, stream>>>(Apool, WcT, P);
  k_reduce    <<<NROIS, 128, 0, stream>>>(P, bc, out);
}

// Round 8
// 223.537 us; speedup vs baseline: 1.8271x; 1.1285x over previous
//
#include <hip/hip_runtime.h>
#include <stdint.h>

// ---------------------------------------------------------------------------
// RoIHead: out = crop_and_resize(feature, rois) @ (W_fc @ [W_loc|W_score])
//                + (b_fc @ [W_loc|W_score] + [b_loc|b_score])
// 413 GF -> 32 GF. Floor: 411 MB W_fc + 100 MB pool = ~81 us HBM.
// R8: base = R6 (best measured fused, 188us alone). ONE change: per-block
// K-phase ROTATION (chunk order (c+mt)&31). W_fc rows are 16KB (2^14); all
// prior rounds had every block read the same 256B column window in lockstep
// -> all addresses congruent below bit 14 -> HBM channel camping at 2.8 TB/s.
// Rotation spreads concurrent reads across all 64 windows (chunk bits + sp
// bit 13) -> full channel coverage. K-sum order is accumulation-invariant.
// ---------------------------------------------------------------------------

typedef float          f32x4 __attribute__((ext_vector_type(4)));
typedef __bf16         bfx8  __attribute__((ext_vector_type(8)));
typedef __bf16         bfx4  __attribute__((ext_vector_type(4)));
typedef __bf16         bfx2  __attribute__((ext_vector_type(2)));

#define KBIG 25088   // 7*7*512
#define NMID 4096    // FC_OUT
#define NROIS 2000
#define G1BLOCKS 784 // 392 m-tiles x 2 k-splits
#define SPLITS 28    // gemm2 K-splits (392 BK steps = 28*14)

__device__ __forceinline__ void gll16(const void* g, void* l) {
  __builtin_amdgcn_global_load_lds(
      (const __attribute__((address_space(1))) void*)(uintptr_t)(g),
      (__attribute__((address_space(3))) void*)(uintptr_t)(l), 16, 0, 0);
}

// ---------------------------------------------------------------------------
// prep: blocks 0..2047 build WcatT[128][4096] bf16 (zero-padded cols>=105);
//       blocks 2048..2175 compute bc[c] = b_fc . Wcat[:,c] + bias[c].
// ---------------------------------------------------------------------------
__global__ __launch_bounds__(256) void k_prep(const float* __restrict__ Wl,
                                              const float* __restrict__ Ws,
                                              const float* __restrict__ bfc,
                                              const float* __restrict__ bl,
                                              const float* __restrict__ bs,
                                              unsigned short* __restrict__ WcatT,
                                              float* __restrict__ bc) {
  if (blockIdx.x < 2048) {
    int idx = blockIdx.x * 256 + threadIdx.x;
    int c = idx >> 12, k = idx & 4095;
    float v = 0.0f;
    if (c < 84)       v = Wl[k * 84 + c];
    else if (c < 105) v = Ws[k * 21 + (c - 84)];
    ((__bf16*)WcatT)[idx] = (__bf16)v;
  } else {
    int c = blockIdx.x - 2048;   // 0..127
    int t = threadIdx.x;
    __shared__ float red[256];
    float p = 0.0f;
    if (c < 105) {
      for (int k = t; k < 4096; k += 256) {
        float w = (c < 84) ? Wl[k * 84 + c] : Ws[k * 21 + (c - 84)];
        p += bfc[k] * w;
      }
    }
    red[t] = p;
    __syncthreads();
    for (int s = 128; s > 0; s >>= 1) {
      if (t < s) red[t] += red[t + s];
      __syncthreads();
    }
    if (t == 0) {
      float bias = (c < 84) ? bl[c] : (c < 105 ? bs[c - 84] : 0.0f);
      bc[c] = (c < 105) ? (red[0] + bias) : 0.0f;
    }
  }
}

// ---------------------------------------------------------------------------
// Fused: blocks [0,784) = GEMM1 (mt = bx>>1, ksplit = bx&1), [784,2784) = pool.
// GEMM1: Pg1[sp][n][m] f32 partial of (W_fc @ WcatT^T)^T.
//   A: coalesced global->reg, cvt (native), swizzled ds_write; prefetch
//      distance = 2 FULL phases (rE feeds even putA, rO feeds odd putA).
//   B: gll16, pre-inverse-swizzled source.
//   K-chunk order ROTATED per block: rc(c) = (c + mt) & 31 (channel spread).
//   Ledger (unchanged from R6): at manual wait, outstanding =
//   B(c)4 A(c+1)4 B(c+1)4 A(c+2)4 = 16; vmcnt(12) retires exactly B(c);
//   putA's compiler reg-dep wait = vmcnt(8). No drain in the loop.
// ---------------------------------------------------------------------------
__global__ __launch_bounds__(256, 3) void k_pool_gemm1(
    const float* __restrict__ F, const float* __restrict__ rois,
    const int* __restrict__ ihp, const int* __restrict__ iwp,
    unsigned short* __restrict__ A,
    const float* __restrict__ Wfc, const unsigned short* __restrict__ WcatT,
    float* __restrict__ Pg1) {
  const int t = threadIdx.x;
  __shared__ __align__(16) char sA[16384];   // [2][64 rows][128 B]
  __shared__ __align__(16) char sB[32768];   // [2][128 rows][128 B]
  if (blockIdx.x < G1BLOCKS) {
    // ---------------- GEMM1 ----------------
    const int lane = t & 63, wid = t >> 6;
    const int l15 = lane & 15, l4 = lane >> 4;
    const int mt = blockIdx.x >> 1, sp = blockIdx.x & 1;
    const int m0 = mt * 64;
    const int kbase = sp * 2048;
    const int rot = mt & 31;
    const int jlog = (t & 7) ^ ((t >> 3) & 7);
    f32x4 acc[8] = {};
    f32x4 rE[4], rO[4];

    const float* abase = Wfc + (size_t)m0 * NMID + kbase;
    const int arw = t >> 4;          // row within 16-row group
    const int acl = (t & 15) * 4;    // float col
    const int ac16 = (t & 15) >> 1;  // 16B chunk within row
    const int ahalf = t & 1;         // 8B half of the chunk

    auto rc = [&](int c) { return (c + rot) & 31; };

    auto loadA = [&](f32x4* d, int c) {
      const int k0 = rc(c) * 64;
#pragma unroll
      for (int i = 0; i < 4; ++i)
        d[i] = *(const f32x4*)(abase + (size_t)(i * 16 + arw) * NMID + k0 + acl);
    };
    auto putA = [&](const f32x4* r, int off) {
#pragma unroll
      for (int i = 0; i < 4; ++i) {
        const int row = i * 16 + arw;
        bfx4 p;
#pragma unroll
        for (int j = 0; j < 4; ++j) p[j] = (__bf16)r[i][j];
        *(bfx4*)(sA + off + row * 128 + ((ac16 ^ (row & 7)) << 4) + ahalf * 8) = p;
      }
    };
    auto stageB = [&](int c, int off) {
      const int k0 = rc(c) * 64;
#pragma unroll
      for (int q = 0; q < 4; ++q)
        gll16(WcatT + (size_t)(q * 32 + (t >> 3)) * NMID + kbase + k0 + jlog * 8,
              sB + off + q * 4096 + wid * 1024);
    };
    auto compute = [&](int aoff, int boff) {
#pragma unroll
      for (int kk = 0; kk < 2; ++kk) {
        const int ar = wid * 16 + l15;
        bfx8 af = *(const bfx8*)(sA + aoff + ar * 128 + ((((kk << 2) + l4) ^ (ar & 7)) << 4));
        bfx8 bfr[8];
#pragma unroll
        for (int nt = 0; nt < 8; ++nt) {
          const int row = nt * 16 + l15;
          bfr[nt] = *(const bfx8*)(sB + boff + row * 128 + ((((kk << 2) + l4) ^ (row & 7)) << 4));
        }
#pragma unroll
        for (int nt = 0; nt < 8; ++nt)
          acc[nt] = __builtin_amdgcn_mfma_f32_16x16x32_bf16(af, bfr[nt], acc[nt], 0, 0, 0);
      }
    };

    // prologue issue order: A(0) < B(0) < A(1)
    loadA(rE, 0);
    __builtin_amdgcn_sched_barrier(0);
    stageB(0, 0);
    __builtin_amdgcn_sched_barrier(0);
    loadA(rO, 1);
    __builtin_amdgcn_sched_barrier(0);

    for (int cc = 0; cc < 16; ++cc) {
      const int c0 = cc * 2;
      // even: compute c0 (sA buf0, sB buf0)
      putA(rE, 0);                             // A(c0), loaded 2 phases ago
      stageB(c0 + 1, 16384);
      __builtin_amdgcn_sched_barrier(0);
      loadA(rE, c0 + 2);                       // wraps via rc() at the tail
      __builtin_amdgcn_sched_barrier(0);
      asm volatile("s_waitcnt vmcnt(12) lgkmcnt(0)" ::: "memory");
      __builtin_amdgcn_s_barrier();
      __builtin_amdgcn_sched_barrier(0);
      compute(0, 0);
      __builtin_amdgcn_s_barrier();
      // odd: compute c0+1 (sA buf1, sB buf1)
      putA(rO, 8192);                          // A(c0+1), loaded 2 phases ago
      stageB(c0 + 2, 0);
      __builtin_amdgcn_sched_barrier(0);
      loadA(rO, c0 + 3);
      __builtin_amdgcn_sched_barrier(0);
      asm volatile("s_waitcnt vmcnt(12) lgkmcnt(0)" ::: "memory");
      __builtin_amdgcn_s_barrier();
      __builtin_amdgcn_sched_barrier(0);
      compute(8192, 16384);
      __builtin_amdgcn_s_barrier();
    }
    asm volatile("s_waitcnt vmcnt(0)" ::: "memory");
    // epilogue: D col(lane&15)=n, row((lane>>4)*4+i)=m -> 16B f32 stores
#pragma unroll
    for (int nt = 0; nt < 8; ++nt) {
      const int n = nt * 16 + l15;
      float* dst = Pg1 + ((size_t)sp * 128 + n) * KBIG + m0 + wid * 16 + l4 * 4;
      *(f32x4*)dst = acc[nt];
    }
  } else {
    // ---------------- pool (next-cell prefetch) ----------------
    const int r = blockIdx.x - G1BLOCKS;
    const float ih = (float)ihp[0], iw = (float)iwp[0];
    const float y1 = rois[r * 4 + 0] / ih;
    const float x1 = rois[r * 4 + 1] / iw;
    const float y2 = rois[r * 4 + 2] / ih;
    const float x2 = rois[r * 4 + 3] / iw;
    const float sy = (y2 - y1) * 49.0f / 6.0f;
    const float sx = (x2 - x1) * 49.0f / 6.0f;
    const int ch = t * 2;
    __bf16* __restrict__ Arow = (__bf16*)(A + (size_t)r * KBIG);

    auto cellcoords = [&](int cell, int& o00, int& o01, int& o10, int& o11,
                          float& yl, float& xl, bool& valid) {
      const int iy = cell / 7, ix = cell - iy * 7;
      const float in_y = y1 * 49.0f + (float)iy * sy;
      const float in_x = x1 * 49.0f + (float)ix * sx;
      const float y0f = floorf(in_y), x0f = floorf(in_x);
      yl = in_y - y0f; xl = in_x - x0f;
      const int y0  = (int)fminf(fmaxf(y0f, 0.0f), 49.0f);
      const int y1i = (int)fminf(fmaxf(y0f + 1.0f, 0.0f), 49.0f);
      const int x0  = (int)fminf(fmaxf(x0f, 0.0f), 49.0f);
      const int x1i = (int)fminf(fmaxf(x0f + 1.0f, 0.0f), 49.0f);
      valid = (in_y >= 0.0f) && (in_y <= 49.0f) && (in_x >= 0.0f) && (in_x <= 49.0f);
      o00 = (y0 * 50 + x0) * 512;  o01 = (y0 * 50 + x1i) * 512;
      o10 = (y1i * 50 + x0) * 512; o11 = (y1i * 50 + x1i) * 512;
    };

    int o00, o01, o10, o11; float yl, xl; bool valid;
    cellcoords(0, o00, o01, o10, o11, yl, xl, valid);
    float2 f00 = *(const float2*)&F[o00 + ch];
    float2 f01 = *(const float2*)&F[o01 + ch];
    float2 f10 = *(const float2*)&F[o10 + ch];
    float2 f11 = *(const float2*)&F[o11 + ch];

    for (int cell = 0; cell < 49; ++cell) {
      const float2 g00 = f00, g01 = f01, g10 = f10, g11 = f11;
      const float pyl = yl, pxl = xl;
      const bool pv = valid;
      if (cell < 48) {
        cellcoords(cell + 1, o00, o01, o10, o11, yl, xl, valid);
        f00 = *(const float2*)&F[o00 + ch];
        f01 = *(const float2*)&F[o01 + ch];
        f10 = *(const float2*)&F[o10 + ch];
        f11 = *(const float2*)&F[o11 + ch];
      }
      float oA = 0.0f, oB = 0.0f;
      if (pv) {
        float t0 = g00.x * (1.0f - pxl) + g01.x * pxl;
        float t1 = g00.y * (1.0f - pxl) + g01.y * pxl;
        float b0 = g10.x * (1.0f - pxl) + g11.x * pxl;
        float b1 = g10.y * (1.0f - pxl) + g11.y * pxl;
        oA = t0 * (1.0f - pyl) + b0 * pyl;
        oB = t1 * (1.0f - pyl) + b1 * pyl;
      }
      bfx2 v; v[0] = (__bf16)oA; v[1] = (__bf16)oB;
      *(bfx2*)(Arow + cell * 512 + ch) = v;
    }
  }
}

// ---------------------------------------------------------------------------
// addcvt: WcT[n][m] bf16 = Pg1[0][n][m] + Pg1[1][n][m]
// ---------------------------------------------------------------------------
__global__ __launch_bounds__(256) void k_addcvt(const float* __restrict__ Pg1,
                                                unsigned short* __restrict__ WcT) {
  const size_t i = ((size_t)blockIdx.x * 256 + threadIdx.x) * 8;  // < 128*25088
  f32x4 a0 = *(const f32x4*)(Pg1 + i);
  f32x4 a1 = *(const f32x4*)(Pg1 + i + 4);
  f32x4 b0 = *(const f32x4*)(Pg1 + 3211264 + i);
  f32x4 b1 = *(const f32x4*)(Pg1 + 3211264 + i + 4);
  bfx8 o;
#pragma unroll
  for (int j = 0; j < 4; ++j) {
    o[j]     = (__bf16)(a0[j] + b0[j]);
    o[j + 4] = (__bf16)(a1[j] + b1[j]);
  }
  *(bfx8*)(WcT + i) = o;
}

// ---------------------------------------------------------------------------
// GEMM2: P[mt*28+sp][64][128] f32 = pool_tile(mt) @ WcT_slice(sp).
// Counted-vmcnt double buffer: stage(c+1); vmcnt(6); barrier; compute(c);
// barrier. One 6-op staging group per region -> count is order-robust.
// ---------------------------------------------------------------------------
__global__ __launch_bounds__(256) void k_gemm2(const unsigned short* __restrict__ Ap,
                                               const unsigned short* __restrict__ WcT,
                                               float* __restrict__ P) {
  __shared__ __align__(16) char S[49152];
  const int t = threadIdx.x;
  const int lane = t & 63, wid = t >> 6;
  const int wm = wid >> 1, wn = wid & 1;
  const int l15 = lane & 15, l4 = lane >> 4;
  const int mt = blockIdx.x, sp = blockIdx.y;
  const int kbase = sp * 896;     // 14 BK-steps of 64
  const int jlog = (t & 7) ^ ((t >> 3) & 7);
  f32x4 acc[2][4] = {};

  int ar0 = mt * 64 + (t >> 3);
  int ar1 = ar0 + 32;
  if (ar0 > NROIS - 1) ar0 = NROIS - 1;
  if (ar1 > NROIS - 1) ar1 = NROIS - 1;
  const unsigned short* asrc0 = Ap + (size_t)ar0 * KBIG + jlog * 8;
  const unsigned short* asrc1 = Ap + (size_t)ar1 * KBIG + jlog * 8;

  auto stage2 = [&](int c, int off) {
    const int k0 = kbase + c * 64;
    gll16(asrc0 + k0, S + off + wid * 1024);
    gll16(asrc1 + k0, S + off + 4096 + wid * 1024);
#pragma unroll
    for (int q = 0; q < 4; ++q)
      gll16(WcT + (size_t)(q * 32 + (t >> 3)) * KBIG + k0 + jlog * 8,
            S + off + 8192 + q * 4096 + wid * 1024);
  };
  auto compute2 = [&](int off) {
#pragma unroll
    for (int kh = 0; kh < 2; ++kh) {
      bfx8 af[2], bfr[4];
#pragma unroll
      for (int mi = 0; mi < 2; ++mi) {
        const int row = wm * 32 + mi * 16 + l15;
        af[mi] = *(const bfx8*)(S + off + row * 128 + ((((kh << 2) + l4) ^ (row & 7)) << 4));
      }
#pragma unroll
      for (int ni = 0; ni < 4; ++ni) {
        const int row = wn * 64 + ni * 16 + l15;
        bfr[ni] = *(const bfx8*)(S + off + 8192 + row * 128 + ((((kh << 2) + l4) ^ (row & 7)) << 4));
      }
#pragma unroll
      for (int mi = 0; mi < 2; ++mi)
#pragma unroll
        for (int ni = 0; ni < 4; ++ni)
          acc[mi][ni] = __builtin_amdgcn_mfma_f32_16x16x32_bf16(af[mi], bfr[ni], acc[mi][ni], 0, 0, 0);
    }
  };

  stage2(0, 0);
  for (int cc = 0; cc < 7; ++cc) {
    const int c0 = cc * 2;
    stage2(c0 + 1, 24576);
    asm volatile("s_waitcnt vmcnt(6)" ::: "memory");
    __builtin_amdgcn_s_barrier();
    __builtin_amdgcn_sched_barrier(0);
    compute2(0);
    __builtin_amdgcn_s_barrier();
    stage2((c0 + 2 < 14) ? c0 + 2 : 13, 0);
    asm volatile("s_waitcnt vmcnt(6)" ::: "memory");
    __builtin_amdgcn_s_barrier();
    __builtin_amdgcn_sched_barrier(0);
    compute2(24576);
    __builtin_amdgcn_s_barrier();
  }
  asm volatile("s_waitcnt vmcnt(0)" ::: "memory");
  float* out = P + (size_t)(mt * SPLITS + sp) * 8192;
#pragma unroll
  for (int mi = 0; mi < 2; ++mi)
#pragma unroll
    for (int ni = 0; ni < 4; ++ni)
#pragma unroll
      for (int i = 0; i < 4; ++i)
        out[(wm * 32 + mi * 16 + l4 * 4 + i) * 128 + wn * 64 + ni * 16 + l15] = acc[mi][ni][i];
}

// ---------------------------------------------------------------------------
// reduce: sum 28 K-split partials + bias, scatter into the two outputs.
// ---------------------------------------------------------------------------
__global__ __launch_bounds__(128) void k_reduce(const float* __restrict__ P,
                                                const float* __restrict__ bc,
                                                float* __restrict__ out) {
  const int m = blockIdx.x;     // 0..1999
  const int c = threadIdx.x;    // 0..127
  if (c >= 105) return;
  const int mt = m >> 6, r = m & 63;
  float sum = 0.0f;
#pragma unroll
  for (int s = 0; s < SPLITS; ++s)
    sum += P[(size_t)(mt * SPLITS + s) * 8192 + r * 128 + c];
  sum += bc[c];
  if (c < 84) out[m * 84 + c] = sum;
  else        out[168000 + m * 21 + (c - 84)] = sum;
}

// ---------------------------------------------------------------------------
extern "C" void kernel_launch(void* const* d_in, const int* in_sizes, int n_in,
                              void* d_out, int out_size, void* d_ws, size_t ws_size,
                              hipStream_t stream) {
  const float* F    = (const float*)d_in[0];
  const float* rois = (const float*)d_in[1];
  const int*   ih   = (const int*)d_in[2];
  const int*   iw   = (const int*)d_in[3];
  const float* Wfc  = (const float*)d_in[4];
  const float* bfc  = (const float*)d_in[5];
  const float* Wl   = (const float*)d_in[6];
  const float* bl   = (const float*)d_in[7];
  const float* Ws   = (const float*)d_in[8];
  const float* bs   = (const float*)d_in[9];
  (void)in_sizes; (void)n_in; (void)out_size; (void)ws_size;

  char* ws = (char*)d_ws;
  // ws layout (bytes):
  //   pool  bf16 [2000][25088]      @ 0          (100,352,000)
  //   WcatT bf16 [128][4096]        @ 100352000  (1,048,576)
  //   WcT   bf16 [128][25088]       @ 101400576  (6,422,528)
  //   bc    f32  [128]              @ 107823104  (512)
  //   P     f32  [896][64][128]     @ 107823616  (29,360,128)
  //   Pg1   f32  [2][128][25088]    @ 137183744  (25,690,112)  total ~163 MB
  unsigned short* Apool = (unsigned short*)(ws);
  unsigned short* WcatT = (unsigned short*)(ws + 100352000);
  unsigned short* WcT   = (unsigned short*)(ws + 101400576);
  float*          bc    = (float*)(ws + 107823104);
  float*          P     = (float*)(ws + 107823616);
  float*          Pg1   = (float*)(ws + 137183744);
  float*          out   = (float*)d_out;

  k_prep      <<<2176, 256, 0, stream>>>(Wl, Ws, bfc, bl, bs, WcatT, bc);
  k_pool_gemm1<<<G1BLOCKS + NROIS, 256, 0, stream>>>(F, rois, ih, iw, Apool,
                                                     Wfc, WcatT, Pg1);
  k_addcvt    <<<1568, 256, 0, stream>>>(Pg1, WcT);
  k_gemm2     <<<dim3(32, SPLITS), 256, 0, stream>>>(Apool, WcT, P);
  k_reduce    <<<NROIS, 128, 0, stream>>>(P, bc, out);
}